// Round 13
// baseline (36.740 us; speedup 1.0000x reference)
//
#include <hip/hip_runtime.h>
#include <hip/hip_bf16.h>

// Reference collapses: softmax over singleton axis==1 -> attention weights == 1,
// so ctx[b,h] = sum_l fmap[b,l,h], out[b,t,c] = dot(ctx[b,:], W_gen[c,:]) + b_gen[c]
// broadcast over all t. LSTM / embedding / text are dead code.
//
// R12 post-mortem: K2 mixes a small GEMM with a 32x-replicated store; no pipe
// saturates and every variant is latency-bound. R13 splits concerns:
//   K1  (R5 verbatim): ctx row-sums                       (~2us)
//   K2': tmp[64][4096] = ctx·W^T + bias, computed ONCE    (~3us, W read ~once)
//   K3 : pure stream broadcast tmp -> out, 33.5MB writes  (~6us at fill-rate)

constexpr int Hd = 512;   // hidden (K)
constexpr int Cd = 4096;  // classes (N)
constexpr int Bd = 64;    // batch (M)
constexpr int Td = 32;    // timesteps (broadcast)
constexpr int Ld = 256;   // FH*FW

// all-DPP 16-lane rotate-add; 0x121:ror1 0x122:ror2 0x124:ror4 0x128:ror8
template<int CTRL>
__device__ __forceinline__ float ror_add(float v) {
    int r = __builtin_amdgcn_update_dpp(0, __float_as_int(v), CTRL, 0xF, 0xF, false);
    return v + __int_as_float(r);
}

// ---------------- K1: ctx[row] = sum of 256 contiguous floats ----------------
// grid 1024 x 256thr; wave = 8 rows, loads all issued up front. (R5 verbatim)
__global__ __launch_bounds__(256) void reduce_rows(const float* __restrict__ in,
                                                   float* __restrict__ ctx) {
    const int lane = threadIdx.x & 63;
    const int gw   = blockIdx.x * 4 + (threadIdx.x >> 6);
    const int row0 = gw * 8;
    const float4* in4 = reinterpret_cast<const float4*>(in);

    float4 v[8];
    #pragma unroll
    for (int r = 0; r < 8; ++r)
        v[r] = in4[(size_t)(row0 + r) * 64 + lane];

    float s[8];
    #pragma unroll
    for (int r = 0; r < 8; ++r) {
        float a = v[r].x + v[r].y + v[r].z + v[r].w;
        a += __shfl_xor(a, 16, 64);
        a += __shfl_xor(a, 32, 64);
        a = ror_add<0x121>(a);
        a = ror_add<0x122>(a);
        a = ror_add<0x124>(a);
        a = ror_add<0x128>(a);
        s[r] = a;
    }
    if (lane < 8) {
        float val = s[0];
        #pragma unroll
        for (int r = 1; r < 8; ++r) val = (lane == r) ? s[r] : val;
        ctx[row0 + lane] = val;
    }
}

// ---------------- K2': tmp[b][c] = ctx[b,:]·W[c,:] + bias (computed once) -------
// grid (Cd/16=256, Bd/16=4) = 1024 blocks, 256 thr (4 waves); block = 16c x 16b.
// Same-cx blocks stride 256 (== 0 mod 8) -> same XCD -> W slice L2-local.
// Lane (cpart,hp): c = cblk + w*4 + cpart; holds wr[j] = W4[c*128 + j*16 + hp]
// (coalesced 256B per 16 lanes; lane's K-elems {j*64 + hp*4..+3}).
// Per b: 8 ctx loads (same mapping, dedup'd across cpart), 32 FMAs, then ONE
// 4-step DPP reduce over the 16 hp lanes. No cross-wave combine.
__global__ __launch_bounds__(256) void gemm_small(const float* __restrict__ ctx,
                                                  const float* __restrict__ Wgen,
                                                  const float* __restrict__ bgen,
                                                  float* __restrict__ tmp) {
    __shared__ float fin[16][16];   // [b_local][c_local]
    const int tid   = threadIdx.x;
    const int w     = tid >> 6;
    const int lane  = tid & 63;
    const int cpart = lane >> 4;
    const int hp    = lane & 15;
    const int cblk  = blockIdx.x * 16;
    const int b0    = blockIdx.y * 16;
    const int c     = cblk + w * 4 + cpart;

    const float4* W4 = reinterpret_cast<const float4*>(Wgen);
    const float4* X4 = reinterpret_cast<const float4*>(ctx);

    float4 wr[8];
    {
        const float4* wp = W4 + (size_t)c * 128 + hp;
        #pragma unroll
        for (int j = 0; j < 8; ++j) wr[j] = wp[j * 16];
    }

    #pragma unroll 2
    for (int bb = 0; bb < 16; ++bb) {
        const float4* xp = X4 + (size_t)(b0 + bb) * 128 + hp;
        float a = 0.f;
        #pragma unroll
        for (int j = 0; j < 8; ++j) {
            const float4 x = xp[j * 16];
            a += wr[j].x * x.x + wr[j].y * x.y + wr[j].z * x.z + wr[j].w * x.w;
        }
        a = ror_add<0x128>(a);
        a = ror_add<0x124>(a);
        a = ror_add<0x122>(a);
        a = ror_add<0x121>(a);      // full K=512 sum in every hp lane
        if (hp == 0) fin[bb][w * 4 + cpart] = a;   // disjoint c_l per wave
    }
    __syncthreads();

    {
        const int bl = tid >> 4, cl = tid & 15;
        tmp[(size_t)(b0 + bl) * Cd + cblk + cl] = fin[bl][cl] + bgen[cblk + cl];
    }
}

// ---------------- K3: out[b][t][:] = tmp[b][:], pure write stream ----------------
// 2048 blocks x 256 thr; thread copies 4 float4s. idx bits: [9:0]=c4,
// [14:10]=t, [20:15]=b. Consecutive lanes -> consecutive out AND tmp addrs.
__global__ __launch_bounds__(256) void bcast(const float* __restrict__ tmp,
                                             float* __restrict__ out) {
    const int gid = blockIdx.x * 256 + threadIdx.x;
    const float4* t4 = reinterpret_cast<const float4*>(tmp);
    float4* o4 = reinterpret_cast<float4*>(out);
    #pragma unroll
    for (int k = 0; k < 4; ++k) {
        const int idx = gid + k * 524288;
        const int c4  = idx & 1023;
        const int b   = idx >> 15;
        o4[idx] = t4[b * 1024 + c4];
    }
}

extern "C" void kernel_launch(void* const* d_in, const int* in_sizes, int n_in,
                              void* d_out, int out_size, void* d_ws, size_t ws_size,
                              hipStream_t stream) {
    const float* fmap = (const float*)d_in[0];   // [64,512,8,32]
    const float* Wgen = (const float*)d_in[9];   // [4096,512]
    const float* bgen = (const float*)d_in[10];  // [4096]
    float* out = (float*)d_out;                  // [64,32,4096]
    float* ctx = (float*)d_ws;                               // 128KB
    float* tmp = (float*)((char*)d_ws + (size_t)Bd * Hd * 4);// 1MB

    reduce_rows<<<dim3((Bd * Hd) / (4 * 8)), dim3(256), 0, stream>>>(fmap, ctx);
    gemm_small<<<dim3(Cd / 16, Bd / 16), dim3(256), 0, stream>>>(ctx, Wgen, bgen, tmp);
    bcast<<<dim3(2048), dim3(256), 0, stream>>>(tmp, out);
}